// Round 8
// baseline (274.893 us; speedup 1.0000x reference)
//
#include <hip/hip_runtime.h>
#include <math.h>

#define Bsz 64
#define Nn  256
#define Hh  1024
#define NK  768

typedef __bf16 bf16;
typedef bf16 bf16x4 __attribute__((ext_vector_type(4)));
typedef bf16 bf16x8 __attribute__((ext_vector_type(8)));
typedef float floatx4 __attribute__((ext_vector_type(4)));

#define KT_ROWS   1026          // kTp rows per batch: h = -1 .. 1024
#define KT_BSTRIDE (KT_ROWS * 256)   // 262656 elements per batch

__device__ __forceinline__ void gl_lds16(const bf16* g, bf16* l) {
    __builtin_amdgcn_global_load_lds(
        (__attribute__((address_space(1))) void*)(g),
        (__attribute__((address_space(3))) void*)(l), 16, 0, 0);
}
__device__ __forceinline__ void gl_lds16f(const float* g, float* l) {
    __builtin_amdgcn_global_load_lds(
        (__attribute__((address_space(1))) void*)(g),
        (__attribute__((address_space(3))) void*)(l), 16, 0, 0);
}

// ---------------------------------------------------------------------------
// Transpose: kin[b][i][h] fp32 -> kTp[b][h+1][i] bf16. Tile 64i x 128h.
// fp32 tile streamed global->LDS via global_load_lds (no VGPR roundtrip).
// LDS linear [i][128h]; SOURCE chunk index XOR-swizzled by (i>>3) so the
// transposed read pattern is <=2-way bank conflict while global reads stay
// fully coalesced (XOR key constant per load instruction).
// ---------------------------------------------------------------------------
__global__ __launch_bounds__(256) void transpose_kernel(
    const float* __restrict__ kin, bf16* __restrict__ kTp)
{
    __shared__ float Tf[64 * 128];   // 32 KB
    const int tid = threadIdx.x;
    const int bid = blockIdx.x;
    const int hb = bid & 7, ib = (bid >> 3) & 3, b = bid >> 5;
    const int i0 = ib * 64, h0 = hb * 128;
    const float* src = kin + ((size_t)b << 18);
    bf16* dstb = kTp + (size_t)b * KT_BSTRIDE;

    if (hb == 0 && ib == 0) {
        dstb[tid] = (bf16)0.f;                       // h = -1 row
        dstb[(size_t)1025 * 256 + tid] = (bf16)0.f;  // h = 1024 row
    }
    // LDS chunk c (16B) holds logical (i = c>>5, hq = (c&31) ^ (i>>3)).
    // For load j: c = tid + j*256 -> i>>3 == j, so XOR key is uniform per
    // instruction and each instruction still covers the same 512B spans.
    #pragma unroll
    for (int j = 0; j < 8; ++j) {
        int c  = tid + j * 256;          // 0..2047
        int il = c >> 5;                 // i-local 0..63
        int hq = (c & 31) ^ j;           // swizzled h-quad
        gl_lds16f(src + (size_t)(i0 + il) * Hh + h0 + hq * 4, Tf + c * 4);
    }
    __syncthreads();                     // drains vmcnt (incl. load_lds)
    const int q = tid & 7;
    #pragma unroll
    for (int p = 0; p < 4; ++p) {
        int hl = (tid >> 3) + p * 32;    // h-local 0..127
        bf16x8 o;
        #pragma unroll
        for (int j = 0; j < 8; ++j) {
            int i = q * 8 + j;           // i>>3 == q
            float v = Tf[i * 128 + (((hl >> 2) ^ q) << 2) + (hl & 3)];
            o[j] = (bf16)v;
        }
        *(bf16x8*)&dstb[(size_t)(h0 + hl + 1) * 256 + i0 + q * 8] = o;
    }
}

// ---------------------------------------------------------------------------
// Cast: f (64MB) and W_lin (3MB) fp32 -> bf16. No LDS -> full occupancy.
// All 10 global loads pinned before any store via sched_barrier(0).
// ---------------------------------------------------------------------------
__global__ __launch_bounds__(256) void cast_kernel(
    const float* __restrict__ f, const float* __restrict__ wl,
    bf16* __restrict__ fbf, bf16* __restrict__ wlbf)
{
    const int STR = 524288;              // 2048 blocks * 256 threads
    const int u0  = blockIdx.x * 256 + threadIdx.x;   // 0..STR-1
    float4 a[8];
    #pragma unroll
    for (int k = 0; k < 4; ++k) {
        const float4* s4 = (const float4*)f + ((size_t)(u0 + k * STR) * 2);
        a[2 * k]     = s4[0];
        a[2 * k + 1] = s4[1];
    }
    float4 b0, b1;
    const bool doW = (u0 < 98304);       // uniform per block (blocks 0..383)
    if (doW) {
        const float4* s4 = (const float4*)wl + ((size_t)u0 * 2);
        b0 = s4[0];
        b1 = s4[1];
    }
    __builtin_amdgcn_sched_barrier(0);   // keep all loads issued before stores
    #pragma unroll
    for (int k = 0; k < 4; ++k) {
        bf16x8 o = {(bf16)a[2*k].x, (bf16)a[2*k].y, (bf16)a[2*k].z, (bf16)a[2*k].w,
                    (bf16)a[2*k+1].x, (bf16)a[2*k+1].y, (bf16)a[2*k+1].z, (bf16)a[2*k+1].w};
        ((bf16x8*)fbf)[u0 + k * STR] = o;
    }
    if (doW) {
        bf16x8 o = {(bf16)b0.x, (bf16)b0.y, (bf16)b0.z, (bf16)b0.w,
                    (bf16)b1.x, (bf16)b1.y, (bf16)b1.z, (bf16)b1.w};
        ((bf16x8*)wlbf)[u0] = o;
    }
}

// ---------------------------------------------------------------------------
// Stage 1: C[row=(b,n)][col=o'] = f_bf[row,:] . W_lin[o',:]  (K=1024)
// 128x192 tile (192 = 3 taps x 64 i), BK=64, 4 waves (2m x 2n of 64x96).
// Staging via gl_lds16. Epilogue via LDS (pitch 200): +bias, unscramble to
// wgt3[b][t][n][i], coalesced 16B stores.   (unchanged)
// ---------------------------------------------------------------------------
__global__ __launch_bounds__(256) void gemm1_mfma(
    const bf16* __restrict__ A,    // [16384][1024]
    const bf16* __restrict__ Bw,   // [768][1024]
    const float* __restrict__ bias,
    bf16* __restrict__ wgt3)       // [64*3][256][256]
{
    __shared__ bf16 smem[25600];   // staging As[2][4096]|Bs[2][6144]; epi Cs[128][200]
    bf16* As = smem;
    bf16* Bs = smem + 8192;
    const int tid  = threadIdx.x;
    const int wave = tid >> 6, lane = tid & 63;
    const int row0 = blockIdx.y * 128;
    const int col0 = blockIdx.x * 192;

    const bf16* gA[4]; bf16* lA[4];
    #pragma unroll
    for (int j = 0; j < 4; ++j) {
        int s = tid + j * 256;               // 0..1023
        int reg = s >> 9, rem = s & 511, row = rem >> 2, quad = rem & 3;
        gA[j] = A + (size_t)(row0 + row) * Hh + reg * 32 + quad * 8;
        lA[j] = As + s * 8;
    }
    const bf16* gB[6]; bf16* lB[6];
    #pragma unroll
    for (int j = 0; j < 6; ++j) {
        int s = tid + j * 256;               // 0..1535
        int reg = s / 768, rem = s - reg * 768, row = rem >> 2, quad = rem & 3;
        gB[j] = Bw + (size_t)(col0 + row) * Hh + reg * 32 + quad * 8;
        lB[j] = Bs + s * 8;
    }

    const int wm = wave & 1, wn = wave >> 1;
    const int fm = lane & 15, koct = (lane >> 4) * 8;

    floatx4 zero = {0.f, 0.f, 0.f, 0.f};
    floatx4 acc[4][6];
    #pragma unroll
    for (int i = 0; i < 4; ++i)
        #pragma unroll
        for (int j = 0; j < 6; ++j) acc[i][j] = zero;

    for (int k0 = 0; k0 < Hh; k0 += 64) {
        #pragma unroll
        for (int j = 0; j < 4; ++j) gl_lds16(gA[j] + k0, lA[j]);
        #pragma unroll
        for (int j = 0; j < 6; ++j) gl_lds16(gB[j] + k0, lB[j]);
        __syncthreads();
        #pragma unroll
        for (int q = 0; q < 2; ++q) {
            bf16x8 af[4], bfr[6];
            #pragma unroll
            for (int mt = 0; mt < 4; ++mt)
                af[mt] = *(const bf16x8*)&As[q * 4096 + (wm * 64 + mt * 16 + fm) * 32 + koct];
            #pragma unroll
            for (int nt = 0; nt < 6; ++nt)
                bfr[nt] = *(const bf16x8*)&Bs[q * 6144 + (wn * 96 + nt * 16 + fm) * 32 + koct];
            #pragma unroll
            for (int mt = 0; mt < 4; ++mt)
                #pragma unroll
                for (int nt = 0; nt < 6; ++nt)
                    acc[mt][nt] = __builtin_amdgcn_mfma_f32_16x16x32_bf16(
                        af[mt], bfr[nt], acc[mt][nt], 0, 0, 0);
        }
        __syncthreads();
    }

    // Epilogue: acc -> Cs[128][192] (pitch 200), then coalesced unscramble.
    const int b  = row0 >> 8;
    const int nb = row0 & 255;
    bf16* Cs = smem;
    #pragma unroll
    for (int nt = 0; nt < 6; ++nt) {
        int c = wn * 96 + nt * 16 + fm;
        float bl = bias[col0 + c];
        #pragma unroll
        for (int mt = 0; mt < 4; ++mt) {
            int rb = wm * 64 + mt * 16 + (lane >> 4) * 4;
            #pragma unroll
            for (int r = 0; r < 4; ++r)
                Cs[(rb + r) * 200 + c] = (bf16)(acc[mt][nt][r] + bl);
        }
    }
    __syncthreads();
    const int i0 = blockIdx.x * 64;
    #pragma unroll
    for (int j = 0; j < 12; ++j) {
        int s = tid + j * 256;               // 0..3071
        int t = s >> 10, rem = s & 1023, n = rem >> 3, q8 = rem & 7;
        bf16x8 v;
        #pragma unroll
        for (int u = 0; u < 8; ++u)
            v[u] = Cs[n * 200 + (q8 * 8 + u) * 3 + t];
        *(bf16x8*)&wgt3[((size_t)(b * 3 + t) << 16) + ((size_t)(nb + n) << 8) + i0 + q8 * 8] = v;
    }
}

// ---------------------------------------------------------------------------
// Stage 2: cbuf[b][o][h] = sum_{t,i} wgt3[b][t][o][i] * kTp[b][h+t][i]  (bf16)
// Block = (b, 64-o, 256-h) -> grid 4096. 8 i-chunks of 32; gl_lds16 staging.
// (unchanged)
// ---------------------------------------------------------------------------
__global__ __launch_bounds__(256, 3) void conv_mfma(
    const bf16* __restrict__ kTp,   // [64][1026][256]
    const bf16* __restrict__ wgt3,  // [64*3][256][256]
    bf16* __restrict__ cbuf)        // [64][256][1024] bf16
{
    __shared__ bf16 As[6144];       // [t][o(64)][i(32)]  12 KB
    __shared__ bf16 Ks[8256];       // [row(258)][i(32)]  16.5 KB
    const int tid  = threadIdx.x;
    const int wave = tid >> 6, lane = tid & 63;
    const int b  = blockIdx.z;
    const int o0 = blockIdx.y * 64;
    const int h0 = blockIdx.x * 256;
    const int wm = wave & 1, wn = wave >> 1;
    const int fm = lane & 15, koct = (lane >> 4) * 8;

    const bf16* gA[3]; bf16* lA[3];
    #pragma unroll
    for (int j = 0; j < 3; ++j) {
        int s = tid + j * 256;               // 0..767
        int t = s >> 8, rem = s & 255, o = rem >> 2, iq = rem & 3;
        gA[j] = wgt3 + ((size_t)(b * 3 + t) << 16) + ((size_t)(o0 + o) << 8) + iq * 8;
        lA[j] = As + s * 8;
    }
    const bf16* kb = kTp + (size_t)b * KT_BSTRIDE;
    const bf16* gK[4]; bf16* lK[4];
    #pragma unroll
    for (int j = 0; j < 4; ++j) {
        int s = tid + j * 256;               // 0..1023 -> rows 0..255
        int r = s >> 2, quad = s & 3;
        gK[j] = kb + (size_t)(h0 + r) * 256 + quad * 8;
        lK[j] = Ks + s * 8;
    }

    floatx4 zero = {0.f, 0.f, 0.f, 0.f};
    floatx4 acc[2][8];
    #pragma unroll
    for (int i = 0; i < 2; ++i)
        #pragma unroll
        for (int j = 0; j < 8; ++j) acc[i][j] = zero;

    for (int ic = 0; ic < 8; ++ic) {
        const int i0 = ic * 32;
        __syncthreads();
        #pragma unroll
        for (int j = 0; j < 3; ++j) gl_lds16(gA[j] + i0, lA[j]);
        #pragma unroll
        for (int j = 0; j < 4; ++j) gl_lds16(gK[j] + i0, lK[j]);
        if (tid < 8) {                       // halo rows 256..257
            int r = 256 + (tid >> 2), q = tid & 3;
            bf16x8 v = *(const bf16x8*)&kb[(size_t)(h0 + r) * 256 + i0 + q * 8];
            *(bf16x8*)&Ks[r * 32 + q * 8] = v;
        }
        __syncthreads();
        #pragma unroll
        for (int t = 0; t < 3; ++t) {
            bf16x8 af[2], bfr[8];
            #pragma unroll
            for (int mt = 0; mt < 2; ++mt)
                af[mt] = *(const bf16x8*)&As[t * 2048 + (wm * 32 + mt * 16 + fm) * 32 + koct];
            #pragma unroll
            for (int nt = 0; nt < 8; ++nt)
                bfr[nt] = *(const bf16x8*)&Ks[(wn * 128 + nt * 16 + fm + t) * 32 + koct];
            #pragma unroll
            for (int mt = 0; mt < 2; ++mt)
                #pragma unroll
                for (int nt = 0; nt < 8; ++nt)
                    acc[mt][nt] = __builtin_amdgcn_mfma_f32_16x16x32_bf16(
                        af[mt], bfr[nt], acc[mt][nt], 0, 0, 0);
        }
    }

    #pragma unroll
    for (int mt = 0; mt < 2; ++mt) {
        int o = o0 + wm * 32 + mt * 16 + (lane >> 4) * 4;
        #pragma unroll
        for (int nt = 0; nt < 8; ++nt) {
            int h = h0 + wn * 128 + nt * 16 + fm;
            #pragma unroll
            for (int r = 0; r < 4; ++r)
                cbuf[((size_t)(b * 256 + o + r) << 10) + h] = (bf16)acc[mt][nt][r];
        }
    }
}

// ---------------------------------------------------------------------------
// Stage 3: LayerNorm, 2048 blocks x 8 rows. Loads hoisted, gamma/beta hoisted,
// parity-double-buffered LDS partials.  (unchanged from v3)
// ---------------------------------------------------------------------------
__global__ __launch_bounds__(256) void ln_kernel(
    const bf16* __restrict__ cbuf, const float* __restrict__ gamma,
    const float* __restrict__ beta, float* __restrict__ out)
{
    const int tid  = threadIdx.x;
    const int t    = tid & 127;      // position within row (x8 elems)
    const int half = tid >> 7;       // which row of the pair
    bf16x8 v[4];
    #pragma unroll
    for (int it = 0; it < 4; ++it) {
        const int row = (blockIdx.x << 3) + it * 2 + half;
        v[it] = *(const bf16x8*)(cbuf + ((size_t)row << 10) + t * 8);
    }
    float4 g0  = ((const float4*)gamma)[t * 2];
    float4 g1  = ((const float4*)gamma)[t * 2 + 1];
    float4 be0 = ((const float4*)beta)[t * 2];
    float4 be1 = ((const float4*)beta)[t * 2 + 1];
    __shared__ float r1[2][4], r2[2][4];
    #pragma unroll
    for (int it = 0; it < 4; ++it) {
        const int row = (blockIdx.x << 3) + it * 2 + half;
        float x[8];
        float s1 = 0.f, s2 = 0.f;
        #pragma unroll
        for (int u = 0; u < 8; ++u) {
            x[u] = (float)v[it][u];
            s1 += x[u];
            s2 += x[u] * x[u];
        }
        #pragma unroll
        for (int m = 1; m < 64; m <<= 1) {
            s1 += __shfl_xor(s1, m, 64);
            s2 += __shfl_xor(s2, m, 64);
        }
        const int p = it & 1;
        if ((tid & 63) == 0) { r1[p][tid >> 6] = s1; r2[p][tid >> 6] = s2; }
        __syncthreads();
        float S1 = r1[p][2 * half] + r1[p][2 * half + 1];
        float S2 = r2[p][2 * half] + r2[p][2 * half + 1];
        float mu   = S1 * (1.0f / 1024.0f);
        float var  = S2 * (1.0f / 1024.0f) - mu * mu;
        float rstd = rsqrtf(var + 1e-5f);
        float4 o0, o1;
        o0.x = (x[0] - mu) * rstd * g0.x + be0.x;
        o0.y = (x[1] - mu) * rstd * g0.y + be0.y;
        o0.z = (x[2] - mu) * rstd * g0.z + be0.z;
        o0.w = (x[3] - mu) * rstd * g0.w + be0.w;
        o1.x = (x[4] - mu) * rstd * g1.x + be1.x;
        o1.y = (x[5] - mu) * rstd * g1.y + be1.y;
        o1.z = (x[6] - mu) * rstd * g1.z + be1.z;
        o1.w = (x[7] - mu) * rstd * g1.w + be1.w;
        float* orow = out + ((size_t)row << 10) + t * 8;
        ((float4*)orow)[0] = o0;
        ((float4*)orow)[1] = o1;
    }
}

extern "C" void kernel_launch(void* const* d_in, const int* in_sizes, int n_in,
                              void* d_out, int out_size, void* d_ws, size_t ws_size,
                              hipStream_t stream) {
    const float* f     = (const float*)d_in[0];
    const float* kin   = (const float*)d_in[1];
    const float* W_lin = (const float*)d_in[2];
    const float* b_lin = (const float*)d_in[3];
    const float* gamma = (const float*)d_in[4];
    const float* beta  = (const float*)d_in[5];
    float* out = (float*)d_out;

    char* ws = (char*)d_ws;
    bf16* fbf  = (bf16*)(ws);                   // 33.55 MB (dead after gemm1)
    bf16* cbuf = (bf16*)(ws);                   // 33.55 MB, aliases fbf
    bf16* wlbf = (bf16*)(ws + 33554432);        // 1.57 MB
    bf16* kTp  = (bf16*)(ws + 35127296);        // 33.62 MB
    bf16* wgt3 = (bf16*)(ws + 68747264);        // 25.17 MB -> total ~93.9 MB

    transpose_kernel<<<2048, 256, 0, stream>>>(kin, kTp);
    cast_kernel<<<2048, 256, 0, stream>>>(f, W_lin, fbf, wlbf);
    gemm1_mfma<<<dim3(4, 128), 256, 0, stream>>>(fbf, wlbf, b_lin, wgt3);
    conv_mfma<<<dim3(4, 4, 64), 256, 0, stream>>>(kTp, wgt3, cbuf);
    ln_kernel<<<2048, 256, 0, stream>>>(cbuf, gamma, beta, out);
}

// Round 9
// 274.291 us; speedup vs baseline: 1.0022x; 1.0022x over previous
//
#include <hip/hip_runtime.h>
#include <math.h>

#define Bsz 64
#define Nn  256
#define Hh  1024
#define NK  768

typedef __bf16 bf16;
typedef bf16 bf16x4 __attribute__((ext_vector_type(4)));
typedef bf16 bf16x8 __attribute__((ext_vector_type(8)));
typedef float floatx4 __attribute__((ext_vector_type(4)));

#define KT_ROWS   1026          // kTp rows per batch: h = -1 .. 1024
#define KT_BSTRIDE (KT_ROWS * 256)   // 262656 elements per batch

__device__ __forceinline__ void gl_lds16(const bf16* g, bf16* l) {
    __builtin_amdgcn_global_load_lds(
        (__attribute__((address_space(1))) void*)(g),
        (__attribute__((address_space(3))) void*)(l), 16, 0, 0);
}
__device__ __forceinline__ void gl_lds16f(const float* g, float* l) {
    __builtin_amdgcn_global_load_lds(
        (__attribute__((address_space(1))) void*)(g),
        (__attribute__((address_space(3))) void*)(l), 16, 0, 0);
}

// ---------------------------------------------------------------------------
// Transpose: kin[b][i][h] fp32 -> kTp[b][h+1][i] bf16. Tile 64i x 128h.
// (unchanged from round 3)
// ---------------------------------------------------------------------------
__global__ __launch_bounds__(256) void transpose_kernel(
    const float* __restrict__ kin, bf16* __restrict__ kTp)
{
    __shared__ float Tf[64 * 128];   // 32 KB
    const int tid = threadIdx.x;
    const int bid = blockIdx.x;
    const int hb = bid & 7, ib = (bid >> 3) & 3, b = bid >> 5;
    const int i0 = ib * 64, h0 = hb * 128;
    const float* src = kin + ((size_t)b << 18);
    bf16* dstb = kTp + (size_t)b * KT_BSTRIDE;

    if (hb == 0 && ib == 0) {
        dstb[tid] = (bf16)0.f;                       // h = -1 row
        dstb[(size_t)1025 * 256 + tid] = (bf16)0.f;  // h = 1024 row
    }
    #pragma unroll
    for (int j = 0; j < 8; ++j) {
        int c  = tid + j * 256;          // 0..2047
        int il = c >> 5;                 // i-local 0..63
        int hq = (c & 31) ^ j;           // swizzled h-quad
        gl_lds16f(src + (size_t)(i0 + il) * Hh + h0 + hq * 4, Tf + c * 4);
    }
    __syncthreads();
    const int q = tid & 7;
    #pragma unroll
    for (int p = 0; p < 4; ++p) {
        int hl = (tid >> 3) + p * 32;    // h-local 0..127
        bf16x8 o;
        #pragma unroll
        for (int j = 0; j < 8; ++j) {
            int i = q * 8 + j;           // i>>3 == q
            float v = Tf[i * 128 + (((hl >> 2) ^ q) << 2) + (hl & 3)];
            o[j] = (bf16)v;
        }
        *(bf16x8*)&dstb[(size_t)(h0 + hl + 1) * 256 + i0 + q * 8] = o;
    }
}

// ---------------------------------------------------------------------------
// Cast: f (64MB) and W_lin (3MB) fp32 -> bf16.  (unchanged from round 3)
// ---------------------------------------------------------------------------
__global__ __launch_bounds__(256) void cast_kernel(
    const float* __restrict__ f, const float* __restrict__ wl,
    bf16* __restrict__ fbf, bf16* __restrict__ wlbf)
{
    const int STR = 524288;              // 2048 blocks * 256 threads
    const int u0  = blockIdx.x * 256 + threadIdx.x;   // 0..STR-1
    float4 a[8];
    #pragma unroll
    for (int k = 0; k < 4; ++k) {
        const float4* s4 = (const float4*)f + ((size_t)(u0 + k * STR) * 2);
        a[2 * k]     = s4[0];
        a[2 * k + 1] = s4[1];
    }
    float4 b0, b1;
    const bool doW = (u0 < 98304);
    if (doW) {
        const float4* s4 = (const float4*)wl + ((size_t)u0 * 2);
        b0 = s4[0];
        b1 = s4[1];
    }
    __builtin_amdgcn_sched_barrier(0);
    #pragma unroll
    for (int k = 0; k < 4; ++k) {
        bf16x8 o = {(bf16)a[2*k].x, (bf16)a[2*k].y, (bf16)a[2*k].z, (bf16)a[2*k].w,
                    (bf16)a[2*k+1].x, (bf16)a[2*k+1].y, (bf16)a[2*k+1].z, (bf16)a[2*k+1].w};
        ((bf16x8*)fbf)[u0 + k * STR] = o;
    }
    if (doW) {
        bf16x8 o = {(bf16)b0.x, (bf16)b0.y, (bf16)b0.z, (bf16)b0.w,
                    (bf16)b1.x, (bf16)b1.y, (bf16)b1.z, (bf16)b1.w};
        ((bf16x8*)wlbf)[u0] = o;
    }
}

// ---------------------------------------------------------------------------
// Stage 1 v2: 128x192 tile, PIPELINED half-steps (BK=32, 32 steps).
// Double-buffered staging [2][10240] fits inside the 25600-elem epilogue
// region -> occupancy unchanged. Per step: STAGE(next) -> compute(cur) ->
// ONE barrier (T3 minimal 2-phase: prefetch latency hides under compute).
// ---------------------------------------------------------------------------
__global__ __launch_bounds__(256) void gemm1_mfma(
    const bf16* __restrict__ A,    // [16384][1024]
    const bf16* __restrict__ Bw,   // [768][1024]
    const float* __restrict__ bias,
    bf16* __restrict__ wgt3)       // [64*3][256][256]
{
    __shared__ bf16 smem[25600];   // dbuf [2][As 4096 | Bs 6144]; epi Cs[128][200]
    const int tid  = threadIdx.x;
    const int wave = tid >> 6, lane = tid & 63;
    const int row0 = blockIdx.y * 128;
    const int col0 = blockIdx.x * 192;

    // per-half-step staging pointers (k-offset added per step)
    const bf16* gA[2]; int lA[2];
    #pragma unroll
    for (int j = 0; j < 2; ++j) {
        int s = tid + j * 256;               // 0..511
        int row = s >> 2, quad = s & 3;
        gA[j] = A + (size_t)(row0 + row) * Hh + quad * 8;
        lA[j] = s * 8;                        // [0,4096)
    }
    const bf16* gB[3]; int lB[3];
    #pragma unroll
    for (int j = 0; j < 3; ++j) {
        int s = tid + j * 256;               // 0..767
        int row = s >> 2, quad = s & 3;
        gB[j] = Bw + (size_t)(col0 + row) * Hh + quad * 8;
        lB[j] = 4096 + s * 8;                 // [4096,10240)
    }

    const int wm = wave & 1, wn = wave >> 1;
    const int fm = lane & 15, koct = (lane >> 4) * 8;

    floatx4 zero = {0.f, 0.f, 0.f, 0.f};
    floatx4 acc[4][6];
    #pragma unroll
    for (int i = 0; i < 4; ++i)
        #pragma unroll
        for (int j = 0; j < 6; ++j) acc[i][j] = zero;

    // prologue: stage half-step 0 into buffer 0
    #pragma unroll
    for (int j = 0; j < 2; ++j) gl_lds16(gA[j], &smem[lA[j]]);
    #pragma unroll
    for (int j = 0; j < 3; ++j) gl_lds16(gB[j], &smem[lB[j]]);
    __syncthreads();

    int cur = 0;
    for (int hs = 0; hs < 32; ++hs) {
        if (hs < 31) {                        // issue next half-step's loads
            const int ko = (hs + 1) * 32;
            const int nb = (cur ^ 1) * 10240;
            #pragma unroll
            for (int j = 0; j < 2; ++j) gl_lds16(gA[j] + ko, &smem[nb + lA[j]]);
            #pragma unroll
            for (int j = 0; j < 3; ++j) gl_lds16(gB[j] + ko, &smem[nb + lB[j]]);
        }
        const int cb = cur * 10240;
        bf16x8 af[4], bfr[6];
        #pragma unroll
        for (int mt = 0; mt < 4; ++mt)
            af[mt] = *(const bf16x8*)&smem[cb + (wm * 64 + mt * 16 + fm) * 32 + koct];
        #pragma unroll
        for (int nt = 0; nt < 6; ++nt)
            bfr[nt] = *(const bf16x8*)&smem[cb + 4096 + (wn * 96 + nt * 16 + fm) * 32 + koct];
        #pragma unroll
        for (int mt = 0; mt < 4; ++mt)
            #pragma unroll
            for (int nt = 0; nt < 6; ++nt)
                acc[mt][nt] = __builtin_amdgcn_mfma_f32_16x16x32_bf16(
                    af[mt], bfr[nt], acc[mt][nt], 0, 0, 0);
        __syncthreads();                      // drains next-buf loads AFTER compute
        cur ^= 1;
    }

    // Epilogue: acc -> Cs[128][192] (pitch 200), then coalesced unscramble.
    const int b  = row0 >> 8;
    const int nb = row0 & 255;
    bf16* Cs = smem;
    #pragma unroll
    for (int nt = 0; nt < 6; ++nt) {
        int c = wn * 96 + nt * 16 + fm;
        float bl = bias[col0 + c];
        #pragma unroll
        for (int mt = 0; mt < 4; ++mt) {
            int rb = wm * 64 + mt * 16 + (lane >> 4) * 4;
            #pragma unroll
            for (int r = 0; r < 4; ++r)
                Cs[(rb + r) * 200 + c] = (bf16)(acc[mt][nt][r] + bl);
        }
    }
    __syncthreads();
    const int i0 = blockIdx.x * 64;
    #pragma unroll
    for (int j = 0; j < 12; ++j) {
        int s = tid + j * 256;               // 0..3071
        int t = s >> 10, rem = s & 1023, n = rem >> 3, q8 = rem & 7;
        bf16x8 v;
        #pragma unroll
        for (int u = 0; u < 8; ++u)
            v[u] = Cs[n * 200 + (q8 * 8 + u) * 3 + t];
        *(bf16x8*)&wgt3[((size_t)(b * 3 + t) << 16) + ((size_t)(nb + n) << 8) + i0 + q8 * 8] = v;
    }
}

// ---------------------------------------------------------------------------
// Stage 2 v2: PIPELINED conv. Double-buffered As/Ks (56.3 KB -> 2 blocks/CU).
// Per i-chunk: STAGE(next buf: halo load first, 7x gl_lds16) -> compute(cur)
// -> halo ds_write(next) -> ONE barrier. Prefetch latency hides under the
// 48-MFMA compute phase instead of being fully exposed (was 2 barriers/chunk).
// ---------------------------------------------------------------------------
__global__ __launch_bounds__(256, 2) void conv_mfma(
    const bf16* __restrict__ kTp,   // [64][1026][256]
    const bf16* __restrict__ wgt3,  // [64*3][256][256]
    bf16* __restrict__ cbuf)        // [64][256][1024] bf16
{
    __shared__ bf16 As[2][6144];    // [buf][t][o(64)][i(32)]  2x12 KB
    __shared__ bf16 Ks[2][8256];    // [buf][row(258)][i(32)]  2x16.5 KB
    const int tid  = threadIdx.x;
    const int wave = tid >> 6, lane = tid & 63;
    const int b  = blockIdx.z;
    const int o0 = blockIdx.y * 64;
    const int h0 = blockIdx.x * 256;
    const int wm = wave & 1, wn = wave >> 1;
    const int fm = lane & 15, koct = (lane >> 4) * 8;

    const bf16* gA[3]; int lA[3];
    #pragma unroll
    for (int j = 0; j < 3; ++j) {
        int s = tid + j * 256;               // 0..767
        int t = s >> 8, rem = s & 255, o = rem >> 2, iq = rem & 3;
        gA[j] = wgt3 + ((size_t)(b * 3 + t) << 16) + ((size_t)(o0 + o) << 8) + iq * 8;
        lA[j] = s * 8;
    }
    const bf16* kb = kTp + (size_t)b * KT_BSTRIDE;
    const bf16* gK[4]; int lK[4];
    #pragma unroll
    for (int j = 0; j < 4; ++j) {
        int s = tid + j * 256;               // 0..1023 -> rows 0..255
        int r = s >> 2, quad = s & 3;
        gK[j] = kb + (size_t)(h0 + r) * 256 + quad * 8;
        lK[j] = s * 8;
    }
    // halo rows 256..257 (8 threads x 16B)
    const bf16* gH = kb + (size_t)(h0 + 256 + (tid >> 2)) * 256 + (tid & 3) * 8;
    const int lH = (256 + (tid >> 2)) * 32 + (tid & 3) * 8;

    floatx4 zero = {0.f, 0.f, 0.f, 0.f};
    floatx4 acc[2][8];
    #pragma unroll
    for (int i = 0; i < 2; ++i)
        #pragma unroll
        for (int j = 0; j < 8; ++j) acc[i][j] = zero;

    // prologue: stage i-chunk 0 into buffer 0
    bf16x8 hv;
    if (tid < 8) hv = *(const bf16x8*)gH;
    #pragma unroll
    for (int j = 0; j < 3; ++j) gl_lds16(gA[j], &As[0][lA[j]]);
    #pragma unroll
    for (int j = 0; j < 4; ++j) gl_lds16(gK[j], &Ks[0][lK[j]]);
    if (tid < 8) *(bf16x8*)&Ks[0][lH] = hv;
    __syncthreads();

    int cur = 0;
    for (int ic = 0; ic < 8; ++ic) {
        const int nxo = (ic + 1) * 32;       // next i-chunk offset
        bf16x8 hn;
        if (ic < 7) {                        // issue next chunk's loads first
            if (tid < 8) hn = *(const bf16x8*)(gH + nxo);
            #pragma unroll
            for (int j = 0; j < 3; ++j) gl_lds16(gA[j] + nxo, &As[cur ^ 1][lA[j]]);
            #pragma unroll
            for (int j = 0; j < 4; ++j) gl_lds16(gK[j] + nxo, &Ks[cur ^ 1][lK[j]]);
        }
        // compute current buffer
        #pragma unroll
        for (int t = 0; t < 3; ++t) {
            bf16x8 af[2], bfr[8];
            #pragma unroll
            for (int mt = 0; mt < 2; ++mt)
                af[mt] = *(const bf16x8*)&As[cur][t * 2048 + (wm * 32 + mt * 16 + fm) * 32 + koct];
            #pragma unroll
            for (int nt = 0; nt < 8; ++nt)
                bfr[nt] = *(const bf16x8*)&Ks[cur][(wn * 128 + nt * 16 + fm + t) * 32 + koct];
            #pragma unroll
            for (int mt = 0; mt < 2; ++mt)
                #pragma unroll
                for (int nt = 0; nt < 8; ++nt)
                    acc[mt][nt] = __builtin_amdgcn_mfma_f32_16x16x32_bf16(
                        af[mt], bfr[nt], acc[mt][nt], 0, 0, 0);
        }
        // halo write AFTER compute so its waitcnt doesn't serialize the stage
        if (ic < 7 && tid < 8) *(bf16x8*)&Ks[cur ^ 1][lH] = hn;
        __syncthreads();                     // single drain per chunk
        cur ^= 1;
    }

    #pragma unroll
    for (int mt = 0; mt < 2; ++mt) {
        int o = o0 + wm * 32 + mt * 16 + (lane >> 4) * 4;
        #pragma unroll
        for (int nt = 0; nt < 8; ++nt) {
            int h = h0 + wn * 128 + nt * 16 + fm;
            #pragma unroll
            for (int r = 0; r < 4; ++r)
                cbuf[((size_t)(b * 256 + o + r) << 10) + h] = (bf16)acc[mt][nt][r];
        }
    }
}

// ---------------------------------------------------------------------------
// Stage 3: LayerNorm, 2048 blocks x 8 rows.  (unchanged from round 3)
// ---------------------------------------------------------------------------
__global__ __launch_bounds__(256) void ln_kernel(
    const bf16* __restrict__ cbuf, const float* __restrict__ gamma,
    const float* __restrict__ beta, float* __restrict__ out)
{
    const int tid  = threadIdx.x;
    const int t    = tid & 127;
    const int half = tid >> 7;
    bf16x8 v[4];
    #pragma unroll
    for (int it = 0; it < 4; ++it) {
        const int row = (blockIdx.x << 3) + it * 2 + half;
        v[it] = *(const bf16x8*)(cbuf + ((size_t)row << 10) + t * 8);
    }
    float4 g0  = ((const float4*)gamma)[t * 2];
    float4 g1  = ((const float4*)gamma)[t * 2 + 1];
    float4 be0 = ((const float4*)beta)[t * 2];
    float4 be1 = ((const float4*)beta)[t * 2 + 1];
    __shared__ float r1[2][4], r2[2][4];
    #pragma unroll
    for (int it = 0; it < 4; ++it) {
        const int row = (blockIdx.x << 3) + it * 2 + half;
        float x[8];
        float s1 = 0.f, s2 = 0.f;
        #pragma unroll
        for (int u = 0; u < 8; ++u) {
            x[u] = (float)v[it][u];
            s1 += x[u];
            s2 += x[u] * x[u];
        }
        #pragma unroll
        for (int m = 1; m < 64; m <<= 1) {
            s1 += __shfl_xor(s1, m, 64);
            s2 += __shfl_xor(s2, m, 64);
        }
        const int p = it & 1;
        if ((tid & 63) == 0) { r1[p][tid >> 6] = s1; r2[p][tid >> 6] = s2; }
        __syncthreads();
        float S1 = r1[p][2 * half] + r1[p][2 * half + 1];
        float S2 = r2[p][2 * half] + r2[p][2 * half + 1];
        float mu   = S1 * (1.0f / 1024.0f);
        float var  = S2 * (1.0f / 1024.0f) - mu * mu;
        float rstd = rsqrtf(var + 1e-5f);
        float4 o0, o1;
        o0.x = (x[0] - mu) * rstd * g0.x + be0.x;
        o0.y = (x[1] - mu) * rstd * g0.y + be0.y;
        o0.z = (x[2] - mu) * rstd * g0.z + be0.z;
        o0.w = (x[3] - mu) * rstd * g0.w + be0.w;
        o1.x = (x[4] - mu) * rstd * g1.x + be1.x;
        o1.y = (x[5] - mu) * rstd * g1.y + be1.y;
        o1.z = (x[6] - mu) * rstd * g1.z + be1.z;
        o1.w = (x[7] - mu) * rstd * g1.w + be1.w;
        float* orow = out + ((size_t)row << 10) + t * 8;
        ((float4*)orow)[0] = o0;
        ((float4*)orow)[1] = o1;
    }
}

extern "C" void kernel_launch(void* const* d_in, const int* in_sizes, int n_in,
                              void* d_out, int out_size, void* d_ws, size_t ws_size,
                              hipStream_t stream) {
    const float* f     = (const float*)d_in[0];
    const float* kin   = (const float*)d_in[1];
    const float* W_lin = (const float*)d_in[2];
    const float* b_lin = (const float*)d_in[3];
    const float* gamma = (const float*)d_in[4];
    const float* beta  = (const float*)d_in[5];
    float* out = (float*)d_out;

    char* ws = (char*)d_ws;
    bf16* fbf  = (bf16*)(ws);                   // 33.55 MB (dead after gemm1)
    bf16* cbuf = (bf16*)(ws);                   // 33.55 MB, aliases fbf
    bf16* wlbf = (bf16*)(ws + 33554432);        // 1.57 MB
    bf16* kTp  = (bf16*)(ws + 35127296);        // 33.62 MB
    bf16* wgt3 = (bf16*)(ws + 68747264);        // 25.17 MB -> total ~93.9 MB

    transpose_kernel<<<2048, 256, 0, stream>>>(kin, kTp);
    cast_kernel<<<2048, 256, 0, stream>>>(f, W_lin, fbf, wlbf);
    gemm1_mfma<<<dim3(4, 128), 256, 0, stream>>>(fbf, wlbf, b_lin, wgt3);
    conv_mfma<<<dim3(4, 4, 64), 256, 0, stream>>>(kTp, wgt3, cbuf);
    ln_kernel<<<2048, 256, 0, stream>>>(cbuf, gamma, beta, out);
}

// Round 10
// 259.752 us; speedup vs baseline: 1.0583x; 1.0560x over previous
//
#include <hip/hip_runtime.h>
#include <math.h>

#define Bsz 64
#define Nn  256
#define Hh  1024
#define NK  768

typedef __bf16 bf16;
typedef bf16 bf16x4 __attribute__((ext_vector_type(4)));
typedef bf16 bf16x8 __attribute__((ext_vector_type(8)));
typedef float floatx4 __attribute__((ext_vector_type(4)));

#define KT_ROWS   1026          // kTp rows per batch: h = -1 .. 1024
#define KT_BSTRIDE (KT_ROWS * 256)   // 262656 elements per batch

__device__ __forceinline__ void gl_lds16(const bf16* g, bf16* l) {
    __builtin_amdgcn_global_load_lds(
        (__attribute__((address_space(1))) void*)(g),
        (__attribute__((address_space(3))) void*)(l), 16, 0, 0);
}
__device__ __forceinline__ void gl_lds16f(const float* g, float* l) {
    __builtin_amdgcn_global_load_lds(
        (__attribute__((address_space(1))) void*)(g),
        (__attribute__((address_space(3))) void*)(l), 16, 0, 0);
}

// ---------------------------------------------------------------------------
// Transpose: kin[b][i][h] fp32 -> kTp[b][h+1][i] bf16. Tile 64i x 128h.
// (unchanged)
// ---------------------------------------------------------------------------
__global__ __launch_bounds__(256) void transpose_kernel(
    const float* __restrict__ kin, bf16* __restrict__ kTp)
{
    __shared__ float Tf[64 * 128];   // 32 KB
    const int tid = threadIdx.x;
    const int bid = blockIdx.x;
    const int hb = bid & 7, ib = (bid >> 3) & 3, b = bid >> 5;
    const int i0 = ib * 64, h0 = hb * 128;
    const float* src = kin + ((size_t)b << 18);
    bf16* dstb = kTp + (size_t)b * KT_BSTRIDE;

    if (hb == 0 && ib == 0) {
        dstb[tid] = (bf16)0.f;                       // h = -1 row
        dstb[(size_t)1025 * 256 + tid] = (bf16)0.f;  // h = 1024 row
    }
    #pragma unroll
    for (int j = 0; j < 8; ++j) {
        int c  = tid + j * 256;          // 0..2047
        int il = c >> 5;                 // i-local 0..63
        int hq = (c & 31) ^ j;           // swizzled h-quad
        gl_lds16f(src + (size_t)(i0 + il) * Hh + h0 + hq * 4, Tf + c * 4);
    }
    __syncthreads();
    const int q = tid & 7;
    #pragma unroll
    for (int p = 0; p < 4; ++p) {
        int hl = (tid >> 3) + p * 32;    // h-local 0..127
        bf16x8 o;
        #pragma unroll
        for (int j = 0; j < 8; ++j) {
            int i = q * 8 + j;           // i>>3 == q
            float v = Tf[i * 128 + (((hl >> 2) ^ q) << 2) + (hl & 3)];
            o[j] = (bf16)v;
        }
        *(bf16x8*)&dstb[(size_t)(h0 + hl + 1) * 256 + i0 + q * 8] = o;
    }
}

// ---------------------------------------------------------------------------
// Stage 1 v3 (FUSED CAST): reads f and W_lin as fp32 directly; reg-stage +
// cvt + ds_write_b64 (linear, conflict-free). cast_kernel eliminated.
// XCD swizzle: the 4 col-blocks of each row-panel share an XCD -> A-panel
// re-reads hit that XCD's L2. 128x192 tile, BK=64, 2-barrier loop.
// ---------------------------------------------------------------------------
__global__ __launch_bounds__(256) void gemm1_mfma(
    const float* __restrict__ A,    // f fp32 [16384][1024]
    const float* __restrict__ Bw,   // W_lin fp32 [768][1024]
    const float* __restrict__ bias,
    bf16* __restrict__ wgt3)        // [64*3][256][256]
{
    __shared__ bf16 smem[25600];    // As[128][64] | Bs[192][64] = 20480; epi Cs[128][200]
    const int tid  = threadIdx.x;
    const int wave = tid >> 6, lane = tid & 63;
    // XCD swizzle (grid 512 = 8 XCD x 64): xcd = bid&7; 16 row-panels per XCD,
    // the 4 col-blocks of a panel are consecutive loc -> same XCD.
    const int bid = blockIdx.x;
    const int xcd = bid & 7, loc = bid >> 3;      // loc 0..63
    const int ry  = (xcd << 4) | (loc >> 2);      // row-panel 0..127
    const int cx  = loc & 3;                      // col-block 0..3
    const int row0 = ry * 128;
    const int col0 = cx * 192;

    // per-thread chunk offsets (16B fp32 chunks; LDS bf16 8B chunks, linear)
    size_t offA[8];                 // A: 128x64 fp32 = 2048 chunks, 8/thread
    #pragma unroll
    for (int j = 0; j < 8; ++j) {
        int c = tid + j * 256, row = c >> 4, kq = c & 15;
        offA[j] = (size_t)(row0 + row) * Hh + kq * 4;
    }
    size_t offB[12];                // B: 192x64 fp32 = 3072 chunks, 12/thread
    #pragma unroll
    for (int j = 0; j < 12; ++j) {
        int c = tid + j * 256, row = c >> 4, kq = c & 15;
        offB[j] = (size_t)(col0 + row) * Hh + kq * 4;
    }

    const int wm = wave & 1, wn = wave >> 1;
    const int fm = lane & 15, koct = (lane >> 4) * 8;

    floatx4 zero = {0.f, 0.f, 0.f, 0.f};
    floatx4 acc[4][6];
    #pragma unroll
    for (int i = 0; i < 4; ++i)
        #pragma unroll
        for (int j = 0; j < 6; ++j) acc[i][j] = zero;

    for (int k0 = 0; k0 < Hh; k0 += 64) {
        // batched fp32 loads (issued while other waves compute)
        float4 av[8];
        #pragma unroll
        for (int j = 0; j < 8; ++j) av[j] = *(const float4*)&A[offA[j] + k0];
        float4 bv[12];
        #pragma unroll
        for (int j = 0; j < 12; ++j) bv[j] = *(const float4*)&Bw[offB[j] + k0];
        __syncthreads();             // previous compute done reading LDS
        #pragma unroll
        for (int j = 0; j < 8; ++j) {
            int c = tid + j * 256;
            bf16x4 o = {(bf16)av[j].x, (bf16)av[j].y, (bf16)av[j].z, (bf16)av[j].w};
            *(bf16x4*)&smem[c * 4] = o;                  // As: byte c*8, linear
        }
        #pragma unroll
        for (int j = 0; j < 12; ++j) {
            int c = tid + j * 256;
            bf16x4 o = {(bf16)bv[j].x, (bf16)bv[j].y, (bf16)bv[j].z, (bf16)bv[j].w};
            *(bf16x4*)&smem[8192 + c * 4] = o;           // Bs
        }
        __syncthreads();
        #pragma unroll
        for (int q = 0; q < 2; ++q) {
            bf16x8 af[4], bfr[6];
            #pragma unroll
            for (int mt = 0; mt < 4; ++mt)
                af[mt] = *(const bf16x8*)&smem[(wm * 64 + mt * 16 + fm) * 64 + q * 32 + koct];
            #pragma unroll
            for (int nt = 0; nt < 6; ++nt)
                bfr[nt] = *(const bf16x8*)&smem[8192 + (wn * 96 + nt * 16 + fm) * 64 + q * 32 + koct];
            #pragma unroll
            for (int mt = 0; mt < 4; ++mt)
                #pragma unroll
                for (int nt = 0; nt < 6; ++nt)
                    acc[mt][nt] = __builtin_amdgcn_mfma_f32_16x16x32_bf16(
                        af[mt], bfr[nt], acc[mt][nt], 0, 0, 0);
        }
    }
    __syncthreads();                 // before Cs clobbers staging

    // Epilogue: acc -> Cs[128][192] (pitch 200), +bias, unscramble to wgt3.
    const int b  = row0 >> 8;
    const int nb = row0 & 255;
    bf16* Cs = smem;
    #pragma unroll
    for (int nt = 0; nt < 6; ++nt) {
        int c = wn * 96 + nt * 16 + fm;
        float bl = bias[col0 + c];
        #pragma unroll
        for (int mt = 0; mt < 4; ++mt) {
            int rb = wm * 64 + mt * 16 + (lane >> 4) * 4;
            #pragma unroll
            for (int r = 0; r < 4; ++r)
                Cs[(rb + r) * 200 + c] = (bf16)(acc[mt][nt][r] + bl);
        }
    }
    __syncthreads();
    const int i0 = cx * 64;
    #pragma unroll
    for (int j = 0; j < 12; ++j) {
        int s = tid + j * 256;               // 0..3071
        int t = s >> 10, rem = s & 1023, n = rem >> 3, q8 = rem & 7;
        bf16x8 v;
        #pragma unroll
        for (int u = 0; u < 8; ++u)
            v[u] = Cs[n * 200 + (q8 * 8 + u) * 3 + t];
        *(bf16x8*)&wgt3[((size_t)(b * 3 + t) << 16) + ((size_t)(nb + n) << 8) + i0 + q8 * 8] = v;
    }
}

// ---------------------------------------------------------------------------
// Stage 2 v3: h-tile 128 -> grid 2048 (8 blocks/CU offered), single-buffer
// 2-barrier (pipelining proven null in r9). XCD swizzle: all 32 blocks of a
// batch b co-XCD -> kTp panel re-reads (4 o-blocks) hit L2 instead of HBM.
// ---------------------------------------------------------------------------
__global__ __launch_bounds__(256) void conv_mfma(
    const bf16* __restrict__ kTp,   // [64][1026][256]
    const bf16* __restrict__ wgt3,  // [64*3][256][256]
    bf16* __restrict__ cbuf)        // [64][256][1024] bf16
{
    __shared__ bf16 As[6144];       // [t][o(64)][i(32)]  12 KB
    __shared__ bf16 Ks[4160];       // [row(130)][i(32)]  8.3 KB
    const int tid  = threadIdx.x;
    const int wave = tid >> 6, lane = tid & 63;
    // XCD swizzle (grid 2048 = 8 XCD x 256): 8 batches per XCD, 32 blocks/b.
    const int bid = blockIdx.x;
    const int xcd = bid & 7, loc = bid >> 3;      // loc 0..255
    const int b   = (xcd << 3) | (loc >> 5);      // 0..63
    const int rem = loc & 31;
    const int o0  = (rem >> 3) * 64;              // 4 o-tiles
    const int h0  = (rem & 7) * 128;              // 8 h-tiles
    const int wm = wave & 1, wn = wave >> 1;
    const int fm = lane & 15, koct = (lane >> 4) * 8;

    const bf16* gA[3]; bf16* lA[3];
    #pragma unroll
    for (int j = 0; j < 3; ++j) {
        int s = tid + j * 256;               // 0..767
        int t = s >> 8, r2 = s & 255, o = r2 >> 2, iq = r2 & 3;
        gA[j] = wgt3 + ((size_t)(b * 3 + t) << 16) + ((size_t)(o0 + o) << 8) + iq * 8;
        lA[j] = As + s * 8;
    }
    const bf16* kb = kTp + (size_t)b * KT_BSTRIDE;
    const bf16* gK[2]; bf16* lK[2];
    #pragma unroll
    for (int j = 0; j < 2; ++j) {
        int s = tid + j * 256;               // 0..511 -> rows 0..127
        int r = s >> 2, quad = s & 3;
        gK[j] = kb + (size_t)(h0 + r) * 256 + quad * 8;
        lK[j] = Ks + s * 8;
    }
    // halo rows 128..129
    const bf16* gH = kb + (size_t)(h0 + 128 + (tid >> 2)) * 256 + (tid & 3) * 8;
    const int lH = (128 + (tid >> 2)) * 32 + (tid & 3) * 8;

    floatx4 zero = {0.f, 0.f, 0.f, 0.f};
    floatx4 acc[2][4];
    #pragma unroll
    for (int i = 0; i < 2; ++i)
        #pragma unroll
        for (int j = 0; j < 4; ++j) acc[i][j] = zero;

    for (int ic = 0; ic < 8; ++ic) {
        const int i0 = ic * 32;
        __syncthreads();                     // prev compute done reading LDS
        #pragma unroll
        for (int j = 0; j < 3; ++j) gl_lds16(gA[j] + i0, lA[j]);
        #pragma unroll
        for (int j = 0; j < 2; ++j) gl_lds16(gK[j] + i0, lK[j]);
        if (tid < 8) {
            bf16x8 v = *(const bf16x8*)(gH + i0);
            *(bf16x8*)&Ks[lH] = v;
        }
        __syncthreads();
        #pragma unroll
        for (int t = 0; t < 3; ++t) {
            bf16x8 af[2], bfr[4];
            #pragma unroll
            for (int mt = 0; mt < 2; ++mt)
                af[mt] = *(const bf16x8*)&As[t * 2048 + (wm * 32 + mt * 16 + fm) * 32 + koct];
            #pragma unroll
            for (int nt = 0; nt < 4; ++nt)
                bfr[nt] = *(const bf16x8*)&Ks[(wn * 64 + nt * 16 + fm + t) * 32 + koct];
            #pragma unroll
            for (int mt = 0; mt < 2; ++mt)
                #pragma unroll
                for (int nt = 0; nt < 4; ++nt)
                    acc[mt][nt] = __builtin_amdgcn_mfma_f32_16x16x32_bf16(
                        af[mt], bfr[nt], acc[mt][nt], 0, 0, 0);
        }
    }

    #pragma unroll
    for (int mt = 0; mt < 2; ++mt) {
        int o = o0 + wm * 32 + mt * 16 + (lane >> 4) * 4;
        #pragma unroll
        for (int nt = 0; nt < 4; ++nt) {
            int h = h0 + wn * 64 + nt * 16 + fm;
            #pragma unroll
            for (int r = 0; r < 4; ++r)
                cbuf[((size_t)(b * 256 + o + r) << 10) + h] = (bf16)acc[mt][nt][r];
        }
    }
}

// ---------------------------------------------------------------------------
// Stage 3: LayerNorm, 2048 blocks x 8 rows.  (unchanged)
// ---------------------------------------------------------------------------
__global__ __launch_bounds__(256) void ln_kernel(
    const bf16* __restrict__ cbuf, const float* __restrict__ gamma,
    const float* __restrict__ beta, float* __restrict__ out)
{
    const int tid  = threadIdx.x;
    const int t    = tid & 127;
    const int half = tid >> 7;
    bf16x8 v[4];
    #pragma unroll
    for (int it = 0; it < 4; ++it) {
        const int row = (blockIdx.x << 3) + it * 2 + half;
        v[it] = *(const bf16x8*)(cbuf + ((size_t)row << 10) + t * 8);
    }
    float4 g0  = ((const float4*)gamma)[t * 2];
    float4 g1  = ((const float4*)gamma)[t * 2 + 1];
    float4 be0 = ((const float4*)beta)[t * 2];
    float4 be1 = ((const float4*)beta)[t * 2 + 1];
    __shared__ float r1[2][4], r2[2][4];
    #pragma unroll
    for (int it = 0; it < 4; ++it) {
        const int row = (blockIdx.x << 3) + it * 2 + half;
        float x[8];
        float s1 = 0.f, s2 = 0.f;
        #pragma unroll
        for (int u = 0; u < 8; ++u) {
            x[u] = (float)v[it][u];
            s1 += x[u];
            s2 += x[u] * x[u];
        }
        #pragma unroll
        for (int m = 1; m < 64; m <<= 1) {
            s1 += __shfl_xor(s1, m, 64);
            s2 += __shfl_xor(s2, m, 64);
        }
        const int p = it & 1;
        if ((tid & 63) == 0) { r1[p][tid >> 6] = s1; r2[p][tid >> 6] = s2; }
        __syncthreads();
        float S1 = r1[p][2 * half] + r1[p][2 * half + 1];
        float S2 = r2[p][2 * half] + r2[p][2 * half + 1];
        float mu   = S1 * (1.0f / 1024.0f);
        float var  = S2 * (1.0f / 1024.0f) - mu * mu;
        float rstd = rsqrtf(var + 1e-5f);
        float4 o0, o1;
        o0.x = (x[0] - mu) * rstd * g0.x + be0.x;
        o0.y = (x[1] - mu) * rstd * g0.y + be0.y;
        o0.z = (x[2] - mu) * rstd * g0.z + be0.z;
        o0.w = (x[3] - mu) * rstd * g0.w + be0.w;
        o1.x = (x[4] - mu) * rstd * g1.x + be1.x;
        o1.y = (x[5] - mu) * rstd * g1.y + be1.y;
        o1.z = (x[6] - mu) * rstd * g1.z + be1.z;
        o1.w = (x[7] - mu) * rstd * g1.w + be1.w;
        float* orow = out + ((size_t)row << 10) + t * 8;
        ((float4*)orow)[0] = o0;
        ((float4*)orow)[1] = o1;
    }
}

extern "C" void kernel_launch(void* const* d_in, const int* in_sizes, int n_in,
                              void* d_out, int out_size, void* d_ws, size_t ws_size,
                              hipStream_t stream) {
    const float* f     = (const float*)d_in[0];
    const float* kin   = (const float*)d_in[1];
    const float* W_lin = (const float*)d_in[2];
    const float* b_lin = (const float*)d_in[3];
    const float* gamma = (const float*)d_in[4];
    const float* beta  = (const float*)d_in[5];
    float* out = (float*)d_out;

    char* ws = (char*)d_ws;
    bf16* cbuf = (bf16*)(ws);                   // 33.55 MB
    bf16* kTp  = (bf16*)(ws + 35127296);        // 33.62 MB
    bf16* wgt3 = (bf16*)(ws + 68747264);        // 25.17 MB

    transpose_kernel<<<2048, 256, 0, stream>>>(kin, kTp);
    gemm1_mfma<<<512, 256, 0, stream>>>(f, W_lin, b_lin, wgt3);
    conv_mfma<<<2048, 256, 0, stream>>>(kTp, wgt3, cbuf);
    ln_kernel<<<2048, 256, 0, stream>>>(cbuf, gamma, beta, out);
}